// Round 1
// baseline (557.240 us; speedup 1.0000x reference)
//
#include <hip/hip_runtime.h>
#include <hip/hip_bf16.h>

// ---------------- helpers ----------------
using short8 = __attribute__((ext_vector_type(8))) short;
using f32x4  = __attribute__((ext_vector_type(4))) float;

__device__ __forceinline__ unsigned short f2bf(float f) {
  union { float f; unsigned int u; } x; x.f = f;
  unsigned int r = (x.u + 0x7fffu + ((x.u >> 16) & 1u)) >> 16;
  return (unsigned short)r;
}

__device__ __forceinline__ void gld_lds16(const short* gp, short* lp) {
  __builtin_amdgcn_global_load_lds((const __attribute__((address_space(1))) void*)gp,
                                   (__attribute__((address_space(3))) void*)lp, 16, 0, 0);
}

// ------- merged cast kernel -------------------------------------------------
__global__ __launch_bounds__(256) void cast_all(const float* __restrict__ x,
                                                const float* __restrict__ Wq,
                                                const float* __restrict__ Wk,
                                                const float* __restrict__ Wv,
                                                const float* __restrict__ Wo,
                                                short* __restrict__ xb,
                                                short* __restrict__ U,
                                                short* __restrict__ V,
                                                float4* __restrict__ sums4) {
  const int bid = blockIdx.x;
  const int tid = threadIdx.x;
  if (bid < 9216) {
    const float4* src;
    short* dst;
    const int i = bid * 256 + tid;
    if (bid < 8192) {
      src = (const float4*)x + i;
      dst = xb + 4ll * i;
    } else {
      const int off = i - 2097152;          // 0..262143 within Wo
      src = (const float4*)Wo + off;
      dst = U + 1048576 + 4ll * off;
    }
    float4 f = *src;
    short4 o;
    o.x = (short)f2bf(f.x); o.y = (short)f2bf(f.y);
    o.z = (short)f2bf(f.z); o.w = (short)f2bf(f.w);
    *(short4*)dst = o;
    if (bid < 8) sums4[bid * 256 + tid] = float4{0.f, 0.f, 0.f, 0.f};
  } else {
    // transpose: tile (by,bx) of W -> tile (bx,by) of dst
    __shared__ short tls[64][65];
    const int t  = bid - 9216;
    const int w  = t >> 8;                  // 0=Wq,1=Wk,2=Wv
    const int ti = t & 255;
    const int bx = ti & 15, by = ti >> 4;
    const float* src = (w == 0) ? Wq : (w == 1) ? Wk : Wv;
    short* dst = (w == 0) ? V : (w == 1) ? U : V + 1048576;
    const int r  = tid >> 4;                // 0..15
    const int c4 = (tid & 15) * 4;          // 0..60 step 4
#pragma unroll
    for (int s = 0; s < 4; ++s) {
      float4 f = *(const float4*)(src + (long long)(by * 64 + r + s * 16) * 1024 + bx * 64 + c4);
      tls[r + s * 16][c4 + 0] = (short)f2bf(f.x);
      tls[r + s * 16][c4 + 1] = (short)f2bf(f.y);
      tls[r + s * 16][c4 + 2] = (short)f2bf(f.z);
      tls[r + s * 16][c4 + 3] = (short)f2bf(f.w);
    }
    __syncthreads();
#pragma unroll
    for (int s = 0; s < 4; ++s) {
      const int a = r + s * 16;
      short4 o;
      o.x = tls[c4 + 0][a]; o.y = tls[c4 + 1][a];
      o.z = tls[c4 + 2][a]; o.w = tls[c4 + 3][a];
      *(short4*)(dst + (long long)(bx * 64 + a) * 1024 + by * 64 + c4) = o;
    }
  }
}

// ---------------- m97-style 128x128 GEMM (kept for MODE 1 and MODE 6) ------
template <int MODE>
__global__ __launch_bounds__(256) void gemm_bt(const short* __restrict__ A,
                                               const short* __restrict__ B,
                                               void* __restrict__ Cv,
                                               float* __restrict__ sums,
                                               int K, int ldc, float scale,
                                               long long aStr, long long bStr,
                                               long long cStr, int gy, int ng) {
  __shared__ short lA[128 * 64];
  __shared__ short lB[128 * 64];
  const int bid = blockIdx.x;
  const int bx  = bid / ng;
  const int g   = bid % ng;
  const int by  = g % gy;
  const long long z = g / gy;
  const int tid = threadIdx.x;
  const int w   = tid >> 6;     // wave 0..3
  const int l   = tid & 63;     // lane
  const int wm  = w >> 1, wn = w & 1;
  const long long tm = (long long)by * 128;
  const long long tn = (long long)bx * 128;
  A += z * aStr;
  B += z * bStr;

  const bool swp = (MODE == 2) ? (bx < 8) : true;

  f32x4 acc[4][4] = {};

  const int lr   = l >> 3;                         // row-in-segment
  const int scw  = ((l & 7) ^ (lr & 7)) * 8;       // swizzled fetch chunk (shorts)
  const int q4   = l >> 4;                         // quad
  const int fr   = l & 15;                         // m (or n) within 16-tile
  const int xr   = fr & 7;                         // row-phase for read swizzle

  for (int k0 = 0; k0 < K; k0 += 64) {
#pragma unroll
    for (int t = 0; t < 4; ++t) {
      const int seg = w * 4 + t;
      gld_lds16(A + (tm + seg * 8 + lr) * (long long)K + k0 + scw, &lA[seg * 512]);
      gld_lds16(B + (tn + seg * 8 + lr) * (long long)K + k0 + scw, &lB[seg * 512]);
    }
    __syncthreads();
#pragma unroll
    for (int kk = 0; kk < 64; kk += 32) {
      const int cs = ((((kk >> 3)) + q4) ^ xr) << 3;   // swizzled chunk offset
      short8 af[4], bfr[4];
#pragma unroll
      for (int i = 0; i < 4; ++i)
        af[i] = *(const short8*)&lA[(wm * 64 + i * 16 + fr) * 64 + cs];
#pragma unroll
      for (int j = 0; j < 4; ++j)
        bfr[j] = *(const short8*)&lB[(wn * 64 + j * 16 + fr) * 64 + cs];
      if (swp) {
#pragma unroll
        for (int i = 0; i < 4; ++i)
#pragma unroll
          for (int j = 0; j < 4; ++j)
            acc[i][j] = __builtin_amdgcn_mfma_f32_16x16x32_bf16(bfr[j], af[i], acc[i][j], 0, 0, 0);
      } else {
#pragma unroll
        for (int i = 0; i < 4; ++i)
#pragma unroll
          for (int j = 0; j < 4; ++j)
            acc[i][j] = __builtin_amdgcn_mfma_f32_16x16x32_bf16(af[i], bfr[j], acc[i][j], 0, 0, 0);
      }
    }
    __syncthreads();
  }

  const int rb = (l >> 4) * 4;   // col base within 16-tile (swapped layout)

  if (MODE == 1) {
    unsigned short* dst = (unsigned short*)Cv + z * cStr;
#pragma unroll
    for (int i = 0; i < 4; ++i) {
      const long long row = tm + wm * 64 + i * 16 + fr;
#pragma unroll
      for (int j = 0; j < 4; ++j) {
        const long long colb = tn + wn * 64 + j * 16 + rb;
        short4 pk;
        pk.x = (short)f2bf(acc[i][j][0]); pk.y = (short)f2bf(acc[i][j][1]);
        pk.z = (short)f2bf(acc[i][j][2]); pk.w = (short)f2bf(acc[i][j][3]);
        *(short4*)(dst + row * ldc + colb) = pk;
      }
    }
  } else if (MODE == 2) {
    if (swp) {   // t region: row-major, packed
      unsigned short* dst = (unsigned short*)Cv;
      const int cb0 = (int)tn + wn * 64;
#pragma unroll
      for (int i = 0; i < 4; ++i) {
        const long long row = tm + wm * 64 + i * 16 + fr;
#pragma unroll
        for (int j = 0; j < 4; ++j) {
          const int colb = cb0 + j * 16 + rb;
          short4 pk;
          pk.x = (short)f2bf(acc[i][j][0]); pk.y = (short)f2bf(acc[i][j][1]);
          pk.z = (short)f2bf(acc[i][j][2]); pk.w = (short)f2bf(acc[i][j][3]);
          *(short4*)(dst + row * 1024 + colb) = pk;
        }
      }
    } else {     // vo region: normal layout, pack along sequence dim
      unsigned short* dst = (unsigned short*)Cv + 8388608ll;
      const int cb0 = (int)(tn - 1024) + wn * 64;
#pragma unroll
      for (int i = 0; i < 4; ++i)
#pragma unroll
        for (int j = 0; j < 4; ++j) {
          const long long row0 = tm + wm * 64 + i * 16 + rb;
          const long long b = row0 >> 12, s0 = row0 & 4095;
          const int c = cb0 + j * 16 + fr;
          short4 pk;
          pk.x = (short)f2bf(acc[i][j][0]); pk.y = (short)f2bf(acc[i][j][1]);
          pk.z = (short)f2bf(acc[i][j][2]); pk.w = (short)f2bf(acc[i][j][3]);
          *(short4*)(dst + b * 4194304ll + (long long)c * 4096 + s0) = pk;
        }
    }
  } else if (MODE == 4) {
    unsigned short* dst = (unsigned short*)Cv + z * cStr;
    float* sm = sums + z * 4096;
#pragma unroll
    for (int i = 0; i < 4; ++i) {
      const long long row = tm + wm * 64 + i * 16 + fr;
      float rs = 0.f;
#pragma unroll
      for (int j = 0; j < 4; ++j) {
        const long long colb = tn + wn * 64 + j * 16 + rb;
        short4 pk;
        float e0 = __expf(acc[i][j][0] * scale);
        float e1 = __expf(acc[i][j][1] * scale);
        float e2 = __expf(acc[i][j][2] * scale);
        float e3 = __expf(acc[i][j][3] * scale);
        rs += (e0 + e1) + (e2 + e3);
        pk.x = (short)f2bf(e0); pk.y = (short)f2bf(e1);
        pk.z = (short)f2bf(e2); pk.w = (short)f2bf(e3);
        *(short4*)(dst + row * ldc + colb) = pk;
      }
      rs += __shfl_xor(rs, 16);
      rs += __shfl_xor(rs, 32);
      if (l < 16) atomicAdd(sm + tm + wm * 64 + i * 16 + l, rs);
    }
  } else {  // MODE 6: fp32 normalized output
    float* dst = (float*)Cv + z * cStr;
    const float* sm = sums + z * 4096;
#pragma unroll
    for (int i = 0; i < 4; ++i) {
      const long long row = tm + wm * 64 + i * 16 + fr;
      const float inv = 1.0f / sm[row];
#pragma unroll
      for (int j = 0; j < 4; ++j) {
        const long long colb = tn + wn * 64 + j * 16 + rb;
        f32x4 o;
        o[0] = acc[i][j][0] * inv; o[1] = acc[i][j][1] * inv;
        o[2] = acc[i][j][2] * inv; o[3] = acc[i][j][3] * inv;
        *(f32x4*)(dst + row * ldc + colb) = o;
      }
    }
  }
}

// ---------------- gemm8: 256x256 tile, BK=32, 4-slot LDS rotation ----------
// 512 threads = 8 waves (2M x 4N), per-wave C = 128x64 (8x4 16x16 frags).
// Counted-vmcnt pipeline (T3+T4): iter t issues tile t+2's 4 global_load_lds,
// computes tile t, then s_waitcnt vmcnt(4) + raw s_barrier -> tile t+1
// certified, tile t+2 in flight ACROSS the barrier (never drains to 0).
// Slot (t+2)&3 was last read at iter t-2, two barriers ago -> no race.
// LDS: 4 slots x (A 16KB + B 16KB) = 128 KiB -> 1 block/CU, 2 waves/SIMD.
// XOR swizzle: chunk q of row r stored at q^((r>>1)&3) (4 x 16B chunks per
// 64B row) -> 2-way bank aliasing on ds_read_b128 (free per m136).
template <int MODE>
__global__ __launch_bounds__(512, 2) void gemm8(const short* __restrict__ A,
                                                const short* __restrict__ B,
                                                void* __restrict__ Cv,
                                                float* __restrict__ sums,
                                                int K, int ldc, float scale,
                                                long long aStr, long long bStr,
                                                long long cStr, int gy, int ng) {
  __shared__ __align__(16) short lds[4][2][8192];   // [slot][A/B][256*32]
  const int bid = blockIdx.x;
  const int bx  = bid / ng;
  const int g   = bid % ng;
  const int by  = g % gy;
  const long long z = g / gy;
  const int tid = threadIdx.x;
  const int l   = tid & 63;
  const int w   = tid >> 6;
  const int wm  = w >> 2, wn = w & 3;
  const long long tm = (long long)by * 256;
  const long long tn = (long long)bx * 256;
  A += z * aStr;
  B += z * bStr;

  const bool swp = (MODE == 2) ? (bx < 4) : true;

  f32x4 acc[8][4] = {};

  // staging lane constants: 2 x 16B loads per matrix per tile
  const int i0 = tid, i1 = tid + 512;               // linear 16B indices
  const int r0 = i0 >> 2, q0 = i0 & 3;
  const int r1 = i1 >> 2, q1 = i1 & 3;
  const int sw0 = (q0 ^ ((r0 >> 1) & 3)) * 8;       // pre-swizzled src chunk
  const int sw1 = (q1 ^ ((r1 >> 1) & 3)) * 8;
  const int db0 = (tid & 448) * 8;                  // wave-uniform dest (shorts)
  const int db1 = 4096 + db0;
  const short* Arow0 = A + (tm + r0) * (long long)K + sw0;
  const short* Arow1 = A + (tm + r1) * (long long)K + sw1;
  const short* Brow0 = B + (tn + r0) * (long long)K + sw0;
  const short* Brow1 = B + (tn + r1) * (long long)K + sw1;

  // fragment read offsets (shorts), swizzled
  const int q4 = l >> 4;
  const int fr = l & 15;
  int offA[8], offB[4];
#pragma unroll
  for (int i = 0; i < 8; ++i) {
    const int r = wm * 128 + i * 16 + fr;
    offA[i] = r * 32 + ((q4 ^ ((r >> 1) & 3)) << 3);
  }
#pragma unroll
  for (int j = 0; j < 4; ++j) {
    const int r = wn * 64 + j * 16 + fr;
    offB[j] = r * 32 + ((q4 ^ ((r >> 1) & 3)) << 3);
  }

  const int nt = K >> 5;

#define STAGE8(tt)                                          \
  {                                                         \
    const int s_ = (tt) & 3;                                \
    const int k_ = (tt) << 5;                               \
    gld_lds16(Arow0 + k_, &lds[s_][0][db0]);                \
    gld_lds16(Arow1 + k_, &lds[s_][0][db1]);                \
    gld_lds16(Brow0 + k_, &lds[s_][1][db0]);                \
    gld_lds16(Brow1 + k_, &lds[s_][1][db1]);                \
  }

  STAGE8(0);
  STAGE8(1);
  asm volatile("s_waitcnt vmcnt(4)" ::: "memory");   // tile 0 resident, tile 1 in flight
  __builtin_amdgcn_s_barrier();

  for (int t = 0; t < nt; ++t) {
    if (t + 2 < nt) STAGE8(t + 2);
    const short* sA = &lds[t & 3][0][0];
    const short* sB = &lds[t & 3][1][0];
    short8 bfr[4];
#pragma unroll
    for (int j = 0; j < 4; ++j) bfr[j] = *(const short8*)&sB[offB[j]];
    __builtin_amdgcn_s_setprio(1);
    if (swp) {
#pragma unroll
      for (int i = 0; i < 8; ++i) {
        short8 af = *(const short8*)&sA[offA[i]];
#pragma unroll
        for (int j = 0; j < 4; ++j)
          acc[i][j] = __builtin_amdgcn_mfma_f32_16x16x32_bf16(bfr[j], af, acc[i][j], 0, 0, 0);
      }
    } else {
#pragma unroll
      for (int i = 0; i < 8; ++i) {
        short8 af = *(const short8*)&sA[offA[i]];
#pragma unroll
        for (int j = 0; j < 4; ++j)
          acc[i][j] = __builtin_amdgcn_mfma_f32_16x16x32_bf16(af, bfr[j], acc[i][j], 0, 0, 0);
      }
    }
    __builtin_amdgcn_s_setprio(0);
    if (t + 1 < nt) {
      if (t + 2 < nt) { asm volatile("s_waitcnt vmcnt(4)" ::: "memory"); }
      else            { asm volatile("s_waitcnt vmcnt(0)" ::: "memory"); }
      __builtin_amdgcn_s_barrier();
    }
  }
#undef STAGE8

  const int rb = q4 * 4;   // col base within 16-tile (swapped layout)

  if (MODE == 2) {
    if (swp) {   // t region: row-major, packed
      unsigned short* dst = (unsigned short*)Cv;
      const int cb0 = (int)tn + wn * 64;
#pragma unroll
      for (int i = 0; i < 8; ++i) {
        const long long row = tm + wm * 128 + i * 16 + fr;
#pragma unroll
        for (int j = 0; j < 4; ++j) {
          const int colb = cb0 + j * 16 + rb;
          short4 pk;
          pk.x = (short)f2bf(acc[i][j][0]); pk.y = (short)f2bf(acc[i][j][1]);
          pk.z = (short)f2bf(acc[i][j][2]); pk.w = (short)f2bf(acc[i][j][3]);
          *(short4*)(dst + row * 1024 + colb) = pk;
        }
      }
    } else {     // vo region: pack along sequence dim
      unsigned short* dst = (unsigned short*)Cv + 8388608ll;
      const int cb0 = (int)(tn - 1024) + wn * 64;
#pragma unroll
      for (int i = 0; i < 8; ++i)
#pragma unroll
        for (int j = 0; j < 4; ++j) {
          const long long row0 = tm + wm * 128 + i * 16 + rb;
          const long long b = row0 >> 12, s0 = row0 & 4095;
          const int c = cb0 + j * 16 + fr;
          short4 pk;
          pk.x = (short)f2bf(acc[i][j][0]); pk.y = (short)f2bf(acc[i][j][1]);
          pk.z = (short)f2bf(acc[i][j][2]); pk.w = (short)f2bf(acc[i][j][3]);
          *(short4*)(dst + b * 4194304ll + (long long)c * 4096 + s0) = pk;
        }
    }
  } else {  // MODE 4: exp + row-sum atomics
    unsigned short* dst = (unsigned short*)Cv + z * cStr;
    float* sm = sums + z * 4096;
#pragma unroll
    for (int i = 0; i < 8; ++i) {
      const long long row = tm + wm * 128 + i * 16 + fr;
      float rs = 0.f;
#pragma unroll
      for (int j = 0; j < 4; ++j) {
        const long long colb = tn + wn * 64 + j * 16 + rb;
        short4 pk;
        float e0 = __expf(acc[i][j][0] * scale);
        float e1 = __expf(acc[i][j][1] * scale);
        float e2 = __expf(acc[i][j][2] * scale);
        float e3 = __expf(acc[i][j][3] * scale);
        rs += (e0 + e1) + (e2 + e3);
        pk.x = (short)f2bf(e0); pk.y = (short)f2bf(e1);
        pk.z = (short)f2bf(e2); pk.w = (short)f2bf(e3);
        *(short4*)(dst + row * ldc + colb) = pk;
      }
      rs += __shfl_xor(rs, 16);
      rs += __shfl_xor(rs, 32);
      if (l < 16) atomicAdd(sm + tm + wm * 128 + i * 16 + l, rs);
    }
  }
}

// ---------------- launch ----------------
extern "C" void kernel_launch(void* const* d_in, const int* in_sizes, int n_in,
                              void* d_out, int out_size, void* d_ws, size_t ws_size,
                              hipStream_t stream) {
  const float* x  = (const float*)d_in[0];
  const float* Wq = (const float*)d_in[1];
  const float* Wk = (const float*)d_in[2];
  const float* Wv = (const float*)d_in[3];
  const float* Wo = (const float*)d_in[4];
  float* out = (float*)d_out;

  // Algebra: scores = x·(Wq^T·Wk)·x^T, out = P_norm·x·(Wo·Wv)^T.
  // ws layout (bytes):
  // [0,16M)    xb   8192x1024 bf16
  // [16M,20M)  U    [WkT; Wo]      [20M,24M) V [WqT; WvT]
  // [24M,28M)  W2   [WqkT; Wvo]
  // [28M,44M)  t    8192x1024 bf16  [44M,60M) vt[2][1024][4096] (vo^T)
  // [60M,+32K) sums 8192 fp32 (zeroed in cast_all)
  // [88M,152M) sc   2 x 4096x4096 bf16 scores (batched path)
  char* ws = (char*)d_ws;
  short* xb = (short*)ws;
  short* U  = (short*)(ws + (16ll << 20));
  short* V  = (short*)(ws + (20ll << 20));
  short* W2 = (short*)(ws + (24ll << 20));
  short* t  = (short*)(ws + (28ll << 20));
  short* vt = t + 8388608;
  float* sums = (float*)(ws + (60ll << 20));
  short* sc = (short*)(ws + (88ll << 20));

  const bool batched = ws_size >= 159383552ull;  // need 152 MiB
  dim3 blk(256);
  dim3 blk8(512);

  // casts + 3 weight transposes + zero sums
  cast_all<<<9984, blk, 0, stream>>>(x, Wq, Wk, Wv, Wo, xb, U, V, (float4*)sums);

  // W2 = [WkT·WqT^T ; Wo·WvT^T], z=2: M=N=K=1024
  gemm_bt<1><<<8 * 16, blk, 0, stream>>>(U, V, W2, nullptr, 1024, 1024, 1.f,
                                         1048576ll, 1048576ll, 1048576ll, 8, 16);

  // merged t/vo projection: M=8192, N=2048, K=1024; 256-tiles: x=8, g=32
  gemm8<2><<<8 * 32, blk8, 0, stream>>>(xb, W2, t, nullptr, 1024, 1024, 1.f,
                                        0, 0, 0, 32, 32);

  if (batched) {
    // scores = t·xb^T + exp, both batches: x=16, g=(y16,z2)=32
    gemm8<4><<<16 * 32, blk8, 0, stream>>>(t, xb, sc, sums, 1024, 4096, 0.03125f,
                                           4194304ll, 4194304ll, 16777216ll, 16, 32);
    // P·vo + normalize -> d_out fp32, both batches (old 128-tile kernel)
    gemm_bt<6><<<8 * 64, blk, 0, stream>>>(sc, vt, out, sums, 4096, 1024, 1.f,
                                           16777216ll, 4194304ll, 4194304ll, 32, 64);
  } else {
    for (int b = 0; b < 2; ++b) {
      short* tb  = t  + (long long)b * 4194304;
      short* xbb = xb + (long long)b * 4194304;
      short* vb  = vt + (long long)b * 4194304;
      float* ob  = out + (long long)b * 4194304;
      float* smb = sums + (long long)b * 4096;
      gemm8<4><<<16 * 16, blk8, 0, stream>>>(tb, xbb, sc, smb, 1024, 4096, 0.03125f,
                                             0, 0, 0, 16, 16);
      gemm_bt<6><<<8 * 32, blk, 0, stream>>>(sc, vb, ob, smb, 4096, 1024, 1.f,
                                             0, 0, 0, 32, 32);
    }
  }
}

// Round 2
// 532.971 us; speedup vs baseline: 1.0455x; 1.0455x over previous
//
#include <hip/hip_runtime.h>
#include <hip/hip_bf16.h>

// ---------------- helpers ----------------
using short8 = __attribute__((ext_vector_type(8))) short;
using f32x4  = __attribute__((ext_vector_type(4))) float;

__device__ __forceinline__ unsigned short f2bf(float f) {
  union { float f; unsigned int u; } x; x.f = f;
  unsigned int r = (x.u + 0x7fffu + ((x.u >> 16) & 1u)) >> 16;
  return (unsigned short)r;
}

__device__ __forceinline__ void gld_lds16(const short* gp, short* lp) {
  __builtin_amdgcn_global_load_lds((const __attribute__((address_space(1))) void*)gp,
                                   (__attribute__((address_space(3))) void*)lp, 16, 0, 0);
}

// ------- merged cast kernel -------------------------------------------------
__global__ __launch_bounds__(256) void cast_all(const float* __restrict__ x,
                                                const float* __restrict__ Wq,
                                                const float* __restrict__ Wk,
                                                const float* __restrict__ Wv,
                                                const float* __restrict__ Wo,
                                                short* __restrict__ xb,
                                                short* __restrict__ U,
                                                short* __restrict__ V,
                                                float4* __restrict__ sums4) {
  const int bid = blockIdx.x;
  const int tid = threadIdx.x;
  if (bid < 9216) {
    const float4* src;
    short* dst;
    const int i = bid * 256 + tid;
    if (bid < 8192) {
      src = (const float4*)x + i;
      dst = xb + 4ll * i;
    } else {
      const int off = i - 2097152;          // 0..262143 within Wo
      src = (const float4*)Wo + off;
      dst = U + 1048576 + 4ll * off;
    }
    float4 f = *src;
    short4 o;
    o.x = (short)f2bf(f.x); o.y = (short)f2bf(f.y);
    o.z = (short)f2bf(f.z); o.w = (short)f2bf(f.w);
    *(short4*)dst = o;
    if (bid < 8) sums4[bid * 256 + tid] = float4{0.f, 0.f, 0.f, 0.f};
  } else {
    // transpose: tile (by,bx) of W -> tile (bx,by) of dst
    __shared__ short tls[64][65];
    const int t  = bid - 9216;
    const int w  = t >> 8;                  // 0=Wq,1=Wk,2=Wv
    const int ti = t & 255;
    const int bx = ti & 15, by = ti >> 4;
    const float* src = (w == 0) ? Wq : (w == 1) ? Wk : Wv;
    short* dst = (w == 0) ? V : (w == 1) ? U : V + 1048576;
    const int r  = tid >> 4;                // 0..15
    const int c4 = (tid & 15) * 4;          // 0..60 step 4
#pragma unroll
    for (int s = 0; s < 4; ++s) {
      float4 f = *(const float4*)(src + (long long)(by * 64 + r + s * 16) * 1024 + bx * 64 + c4);
      tls[r + s * 16][c4 + 0] = (short)f2bf(f.x);
      tls[r + s * 16][c4 + 1] = (short)f2bf(f.y);
      tls[r + s * 16][c4 + 2] = (short)f2bf(f.z);
      tls[r + s * 16][c4 + 3] = (short)f2bf(f.w);
    }
    __syncthreads();
#pragma unroll
    for (int s = 0; s < 4; ++s) {
      const int a = r + s * 16;
      short4 o;
      o.x = tls[c4 + 0][a]; o.y = tls[c4 + 1][a];
      o.z = tls[c4 + 2][a]; o.w = tls[c4 + 3][a];
      *(short4*)(dst + (long long)(bx * 64 + a) * 1024 + by * 64 + c4) = o;
    }
  }
}

// ---------------- m97-style 128x128 GEMM (kept for MODE 1 and MODE 6) ------
template <int MODE>
__global__ __launch_bounds__(256) void gemm_bt(const short* __restrict__ A,
                                               const short* __restrict__ B,
                                               void* __restrict__ Cv,
                                               float* __restrict__ sums,
                                               int K, int ldc, float scale,
                                               long long aStr, long long bStr,
                                               long long cStr, int gy, int ng) {
  __shared__ short lA[128 * 64];
  __shared__ short lB[128 * 64];
  const int bid = blockIdx.x;
  const int bx  = bid / ng;
  const int g   = bid % ng;
  const int by  = g % gy;
  const long long z = g / gy;
  const int tid = threadIdx.x;
  const int w   = tid >> 6;     // wave 0..3
  const int l   = tid & 63;     // lane
  const int wm  = w >> 1, wn = w & 1;
  const long long tm = (long long)by * 128;
  const long long tn = (long long)bx * 128;
  A += z * aStr;
  B += z * bStr;

  const bool swp = (MODE == 2) ? (bx < 8) : true;

  f32x4 acc[4][4] = {};

  const int lr   = l >> 3;                         // row-in-segment
  const int scw  = ((l & 7) ^ (lr & 7)) * 8;       // swizzled fetch chunk (shorts)
  const int q4   = l >> 4;                         // quad
  const int fr   = l & 15;                         // m (or n) within 16-tile
  const int xr   = fr & 7;                         // row-phase for read swizzle

  for (int k0 = 0; k0 < K; k0 += 64) {
#pragma unroll
    for (int t = 0; t < 4; ++t) {
      const int seg = w * 4 + t;
      gld_lds16(A + (tm + seg * 8 + lr) * (long long)K + k0 + scw, &lA[seg * 512]);
      gld_lds16(B + (tn + seg * 8 + lr) * (long long)K + k0 + scw, &lB[seg * 512]);
    }
    __syncthreads();
#pragma unroll
    for (int kk = 0; kk < 64; kk += 32) {
      const int cs = ((((kk >> 3)) + q4) ^ xr) << 3;   // swizzled chunk offset
      short8 af[4], bfr[4];
#pragma unroll
      for (int i = 0; i < 4; ++i)
        af[i] = *(const short8*)&lA[(wm * 64 + i * 16 + fr) * 64 + cs];
#pragma unroll
      for (int j = 0; j < 4; ++j)
        bfr[j] = *(const short8*)&lB[(wn * 64 + j * 16 + fr) * 64 + cs];
      if (swp) {
#pragma unroll
        for (int i = 0; i < 4; ++i)
#pragma unroll
          for (int j = 0; j < 4; ++j)
            acc[i][j] = __builtin_amdgcn_mfma_f32_16x16x32_bf16(bfr[j], af[i], acc[i][j], 0, 0, 0);
      } else {
#pragma unroll
        for (int i = 0; i < 4; ++i)
#pragma unroll
          for (int j = 0; j < 4; ++j)
            acc[i][j] = __builtin_amdgcn_mfma_f32_16x16x32_bf16(af[i], bfr[j], acc[i][j], 0, 0, 0);
      }
    }
    __syncthreads();
  }

  const int rb = (l >> 4) * 4;   // col base within 16-tile (swapped layout)

  if (MODE == 1) {
    unsigned short* dst = (unsigned short*)Cv + z * cStr;
#pragma unroll
    for (int i = 0; i < 4; ++i) {
      const long long row = tm + wm * 64 + i * 16 + fr;
#pragma unroll
      for (int j = 0; j < 4; ++j) {
        const long long colb = tn + wn * 64 + j * 16 + rb;
        short4 pk;
        pk.x = (short)f2bf(acc[i][j][0]); pk.y = (short)f2bf(acc[i][j][1]);
        pk.z = (short)f2bf(acc[i][j][2]); pk.w = (short)f2bf(acc[i][j][3]);
        *(short4*)(dst + row * ldc + colb) = pk;
      }
    }
  } else if (MODE == 2) {
    if (swp) {   // t region: row-major, packed
      unsigned short* dst = (unsigned short*)Cv;
      const int cb0 = (int)tn + wn * 64;
#pragma unroll
      for (int i = 0; i < 4; ++i) {
        const long long row = tm + wm * 64 + i * 16 + fr;
#pragma unroll
        for (int j = 0; j < 4; ++j) {
          const int colb = cb0 + j * 16 + rb;
          short4 pk;
          pk.x = (short)f2bf(acc[i][j][0]); pk.y = (short)f2bf(acc[i][j][1]);
          pk.z = (short)f2bf(acc[i][j][2]); pk.w = (short)f2bf(acc[i][j][3]);
          *(short4*)(dst + row * 1024 + colb) = pk;
        }
      }
    } else {     // vo region: normal layout, pack along sequence dim
      unsigned short* dst = (unsigned short*)Cv + 8388608ll;
      const int cb0 = (int)(tn - 1024) + wn * 64;
#pragma unroll
      for (int i = 0; i < 4; ++i)
#pragma unroll
        for (int j = 0; j < 4; ++j) {
          const long long row0 = tm + wm * 64 + i * 16 + rb;
          const long long b = row0 >> 12, s0 = row0 & 4095;
          const int c = cb0 + j * 16 + fr;
          short4 pk;
          pk.x = (short)f2bf(acc[i][j][0]); pk.y = (short)f2bf(acc[i][j][1]);
          pk.z = (short)f2bf(acc[i][j][2]); pk.w = (short)f2bf(acc[i][j][3]);
          *(short4*)(dst + b * 4194304ll + (long long)c * 4096 + s0) = pk;
        }
    }
  } else if (MODE == 4) {
    unsigned short* dst = (unsigned short*)Cv + z * cStr;
    float* sm = sums + z * 4096;
#pragma unroll
    for (int i = 0; i < 4; ++i) {
      const long long row = tm + wm * 64 + i * 16 + fr;
      float rs = 0.f;
#pragma unroll
      for (int j = 0; j < 4; ++j) {
        const long long colb = tn + wn * 64 + j * 16 + rb;
        short4 pk;
        float e0 = __expf(acc[i][j][0] * scale);
        float e1 = __expf(acc[i][j][1] * scale);
        float e2 = __expf(acc[i][j][2] * scale);
        float e3 = __expf(acc[i][j][3] * scale);
        rs += (e0 + e1) + (e2 + e3);
        pk.x = (short)f2bf(e0); pk.y = (short)f2bf(e1);
        pk.z = (short)f2bf(e2); pk.w = (short)f2bf(e3);
        *(short4*)(dst + row * ldc + colb) = pk;
      }
      rs += __shfl_xor(rs, 16);
      rs += __shfl_xor(rs, 32);
      if (l < 16) atomicAdd(sm + tm + wm * 64 + i * 16 + l, rs);
    }
  } else {  // MODE 6: fp32 normalized output
    float* dst = (float*)Cv + z * cStr;
    const float* sm = sums + z * 4096;
#pragma unroll
    for (int i = 0; i < 4; ++i) {
      const long long row = tm + wm * 64 + i * 16 + fr;
      const float inv = 1.0f / sm[row];
#pragma unroll
      for (int j = 0; j < 4; ++j) {
        const long long colb = tn + wn * 64 + j * 16 + rb;
        f32x4 o;
        o[0] = acc[i][j][0] * inv; o[1] = acc[i][j][1] * inv;
        o[2] = acc[i][j][2] * inv; o[3] = acc[i][j][3] * inv;
        *(f32x4*)(dst + row * ldc + colb) = o;
      }
    }
  }
}

// ---------------- gemm8: 256x256 tile, BK=32, 4-slot LDS rotation ----------
// 512 threads = 8 waves (2M x 4N), per-wave C = 128x64 (8x4 16x16 frags).
// Counted-vmcnt pipeline (T3+T4): iter t issues tile t+2's 4 global_load_lds,
// computes tile t, then s_waitcnt vmcnt(4) + raw s_barrier -> tile t+1
// certified, tile t+2 in flight ACROSS the barrier (never drains to 0).
// Slot (t+2)&3 was last read at iter t-2, two barriers ago -> no race.
// LDS: 4 slots x (A 16KB + B 16KB) = 128 KiB -> 1 block/CU, 2 waves/SIMD.
//
// __launch_bounds__(512, 1): under CUDA min-blocks semantics 1 block/CU ->
// 2 waves/EU -> 256-VGPR cap. (512,2) was read as 2 blocks/CU -> 128-VGPR
// cap -> acc alone (128 regs) forced ~690 MB/dispatch of scratch spill
// traffic (r1: WRITE_SIZE 758 MB, MfmaUtil 5%). Do not lower this.
//
// Register diet: the read-swizzle chunk (q4 ^ ((r>>1)&3)) depends only on
// fr bits 1-2 (wm*128, i*16 don't touch bits 1-2) -> offA/offB collapse to
// two scalars + i*512 immediates (fold into ds_read offset:). Staging:
// sw(row+128)==sw(row) and A/B share the per-thread offset -> 2 int offsets
// + 2 uniform bases instead of 4 per-thread 64-bit pointers.
template <int MODE>
__global__ __launch_bounds__(512, 1) void gemm8(const short* __restrict__ A,
                                                const short* __restrict__ B,
                                                void* __restrict__ Cv,
                                                float* __restrict__ sums,
                                                int K, int ldc, float scale,
                                                long long aStr, long long bStr,
                                                long long cStr, int gy, int ng) {
  __shared__ __align__(16) short lds[4][2][8192];   // [slot][A/B][256*32]
  const int bid = blockIdx.x;
  const int bx  = bid / ng;
  const int g   = bid % ng;
  const int by  = g % gy;
  const long long z = g / gy;
  const int tid = threadIdx.x;
  const int l   = tid & 63;
  const int w   = tid >> 6;
  const int wm  = w >> 2, wn = w & 3;
  const long long tm = (long long)by * 256;
  const long long tn = (long long)bx * 256;
  A += z * aStr;
  B += z * bStr;

  const bool swp = (MODE == 2) ? (bx < 4) : true;

  f32x4 acc[8][4] = {};

  // staging: 16B-chunk tid covers row tid>>2, chunk tid&3 (and +128 rows).
  // LDS dest is linear (wave-uniform base + lane*16); source chunk is
  // pre-swizzled so that logical chunk c of row r lands at c^((r>>1)&3).
  const int r0 = tid >> 2, q0 = tid & 3;
  const int sw = (q0 ^ ((r0 >> 1) & 3)) * 8;        // shorts
  const int o0 = r0 * K + sw;                       // per-thread src offset
  const int o1 = o0 + (K << 7);                     // +128 rows (same swizzle)
  const short* Ab = A + tm * (long long)K;
  const short* Bb = B + tn * (long long)K;
  const int db0 = (tid & 448) * 8;                  // wave-uniform dest (shorts)
  const int db1 = 4096 + db0;

  // fragment reads: swizzle chunk constant per thread
  const int q4 = l >> 4;
  const int fr = l & 15;
  const int cw = (q4 ^ ((fr >> 1) & 3)) << 3;
  const int offA0 = (wm * 128 + fr) * 32 + cw;
  const int offB0 = (wn * 64 + fr) * 32 + cw;

  const int nt = K >> 5;

#define STAGE8(tt)                                  \
  {                                                 \
    const int s_ = (tt) & 3;                        \
    const int k_ = (tt) << 5;                       \
    gld_lds16(Ab + o0 + k_, &lds[s_][0][db0]);      \
    gld_lds16(Ab + o1 + k_, &lds[s_][0][db1]);      \
    gld_lds16(Bb + o0 + k_, &lds[s_][1][db0]);      \
    gld_lds16(Bb + o1 + k_, &lds[s_][1][db1]);      \
  }

  STAGE8(0);
  STAGE8(1);
  asm volatile("s_waitcnt vmcnt(4)" ::: "memory");   // tile 0 resident, tile 1 in flight
  __builtin_amdgcn_s_barrier();

  for (int t = 0; t < nt; ++t) {
    if (t + 2 < nt) STAGE8(t + 2);
    const short* sA = &lds[t & 3][0][0];
    const short* sB = &lds[t & 3][1][0];
    short8 bfr[4];
#pragma unroll
    for (int j = 0; j < 4; ++j) bfr[j] = *(const short8*)&sB[offB0 + j * 512];
    __builtin_amdgcn_s_setprio(1);
    if (swp) {
#pragma unroll
      for (int i = 0; i < 8; ++i) {
        short8 af = *(const short8*)&sA[offA0 + i * 512];
#pragma unroll
        for (int j = 0; j < 4; ++j)
          acc[i][j] = __builtin_amdgcn_mfma_f32_16x16x32_bf16(bfr[j], af, acc[i][j], 0, 0, 0);
      }
    } else {
#pragma unroll
      for (int i = 0; i < 8; ++i) {
        short8 af = *(const short8*)&sA[offA0 + i * 512];
#pragma unroll
        for (int j = 0; j < 4; ++j)
          acc[i][j] = __builtin_amdgcn_mfma_f32_16x16x32_bf16(af, bfr[j], acc[i][j], 0, 0, 0);
      }
    }
    __builtin_amdgcn_s_setprio(0);
    if (t + 1 < nt) {
      if (t + 2 < nt) { asm volatile("s_waitcnt vmcnt(4)" ::: "memory"); }
      else            { asm volatile("s_waitcnt vmcnt(0)" ::: "memory"); }
      __builtin_amdgcn_s_barrier();
    }
  }
#undef STAGE8

  const int rb = q4 * 4;   // col base within 16-tile (swapped layout)

  if (MODE == 2) {
    if (swp) {   // t region: row-major, packed
      unsigned short* dst = (unsigned short*)Cv;
      const int cb0 = (int)tn + wn * 64;
#pragma unroll
      for (int i = 0; i < 8; ++i) {
        const long long row = tm + wm * 128 + i * 16 + fr;
#pragma unroll
        for (int j = 0; j < 4; ++j) {
          const int colb = cb0 + j * 16 + rb;
          short4 pk;
          pk.x = (short)f2bf(acc[i][j][0]); pk.y = (short)f2bf(acc[i][j][1]);
          pk.z = (short)f2bf(acc[i][j][2]); pk.w = (short)f2bf(acc[i][j][3]);
          *(short4*)(dst + row * 1024 + colb) = pk;
        }
      }
    } else {     // vo region: pack along sequence dim
      unsigned short* dst = (unsigned short*)Cv + 8388608ll;
      const int cb0 = (int)(tn - 1024) + wn * 64;
#pragma unroll
      for (int i = 0; i < 8; ++i)
#pragma unroll
        for (int j = 0; j < 4; ++j) {
          const long long row0 = tm + wm * 128 + i * 16 + rb;
          const long long b = row0 >> 12, s0 = row0 & 4095;
          const int c = cb0 + j * 16 + fr;
          short4 pk;
          pk.x = (short)f2bf(acc[i][j][0]); pk.y = (short)f2bf(acc[i][j][1]);
          pk.z = (short)f2bf(acc[i][j][2]); pk.w = (short)f2bf(acc[i][j][3]);
          *(short4*)(dst + b * 4194304ll + (long long)c * 4096 + s0) = pk;
        }
    }
  } else {  // MODE 4: exp + row-sum atomics
    unsigned short* dst = (unsigned short*)Cv + z * cStr;
    float* sm = sums + z * 4096;
#pragma unroll
    for (int i = 0; i < 8; ++i) {
      const long long row = tm + wm * 128 + i * 16 + fr;
      float rs = 0.f;
#pragma unroll
      for (int j = 0; j < 4; ++j) {
        const long long colb = tn + wn * 64 + j * 16 + rb;
        short4 pk;
        float e0 = __expf(acc[i][j][0] * scale);
        float e1 = __expf(acc[i][j][1] * scale);
        float e2 = __expf(acc[i][j][2] * scale);
        float e3 = __expf(acc[i][j][3] * scale);
        rs += (e0 + e1) + (e2 + e3);
        pk.x = (short)f2bf(e0); pk.y = (short)f2bf(e1);
        pk.z = (short)f2bf(e2); pk.w = (short)f2bf(e3);
        *(short4*)(dst + row * ldc + colb) = pk;
      }
      rs += __shfl_xor(rs, 16);
      rs += __shfl_xor(rs, 32);
      if (l < 16) atomicAdd(sm + tm + wm * 128 + i * 16 + l, rs);
    }
  }
}

// ---------------- launch ----------------
extern "C" void kernel_launch(void* const* d_in, const int* in_sizes, int n_in,
                              void* d_out, int out_size, void* d_ws, size_t ws_size,
                              hipStream_t stream) {
  const float* x  = (const float*)d_in[0];
  const float* Wq = (const float*)d_in[1];
  const float* Wk = (const float*)d_in[2];
  const float* Wv = (const float*)d_in[3];
  const float* Wo = (const float*)d_in[4];
  float* out = (float*)d_out;

  // Algebra: scores = x·(Wq^T·Wk)·x^T, out = P_norm·x·(Wo·Wv)^T.
  // ws layout (bytes):
  // [0,16M)    xb   8192x1024 bf16
  // [16M,20M)  U    [WkT; Wo]      [20M,24M) V [WqT; WvT]
  // [24M,28M)  W2   [WqkT; Wvo]
  // [28M,44M)  t    8192x1024 bf16  [44M,60M) vt[2][1024][4096] (vo^T)
  // [60M,+32K) sums 8192 fp32 (zeroed in cast_all)
  // [88M,152M) sc   2 x 4096x4096 bf16 scores (batched path)
  char* ws = (char*)d_ws;
  short* xb = (short*)ws;
  short* U  = (short*)(ws + (16ll << 20));
  short* V  = (short*)(ws + (20ll << 20));
  short* W2 = (short*)(ws + (24ll << 20));
  short* t  = (short*)(ws + (28ll << 20));
  short* vt = t + 8388608;
  float* sums = (float*)(ws + (60ll << 20));
  short* sc = (short*)(ws + (88ll << 20));

  const bool batched = ws_size >= 159383552ull;  // need 152 MiB
  dim3 blk(256);
  dim3 blk8(512);

  // casts + 3 weight transposes + zero sums
  cast_all<<<9984, blk, 0, stream>>>(x, Wq, Wk, Wv, Wo, xb, U, V, (float4*)sums);

  // W2 = [WkT·WqT^T ; Wo·WvT^T], z=2: M=N=K=1024
  gemm_bt<1><<<8 * 16, blk, 0, stream>>>(U, V, W2, nullptr, 1024, 1024, 1.f,
                                         1048576ll, 1048576ll, 1048576ll, 8, 16);

  // merged t/vo projection: M=8192, N=2048, K=1024; 256-tiles: x=8, g=32
  gemm8<2><<<8 * 32, blk8, 0, stream>>>(xb, W2, t, nullptr, 1024, 1024, 1.f,
                                        0, 0, 0, 32, 32);

  if (batched) {
    // scores = t·xb^T + exp, both batches: x=16, g=(y16,z2)=32
    gemm8<4><<<16 * 32, blk8, 0, stream>>>(t, xb, sc, sums, 1024, 4096, 0.03125f,
                                           4194304ll, 4194304ll, 16777216ll, 16, 32);
    // P·vo + normalize -> d_out fp32, both batches (old 128-tile kernel)
    gemm_bt<6><<<8 * 64, blk, 0, stream>>>(sc, vt, out, sums, 4096, 1024, 1.f,
                                           16777216ll, 4194304ll, 4194304ll, 32, 64);
  } else {
    for (int b = 0; b < 2; ++b) {
      short* tb  = t  + (long long)b * 4194304;
      short* xbb = xb + (long long)b * 4194304;
      short* vb  = vt + (long long)b * 4194304;
      float* ob  = out + (long long)b * 4194304;
      float* smb = sums + (long long)b * 4096;
      gemm8<4><<<16 * 16, blk8, 0, stream>>>(tb, xbb, sc, smb, 1024, 4096, 0.03125f,
                                             0, 0, 0, 16, 16);
      gemm_bt<6><<<8 * 32, blk, 0, stream>>>(sc, vb, ob, smb, 4096, 1024, 1.f,
                                             0, 0, 0, 32, 32);
    }
  }
}

// Round 4
// 318.333 us; speedup vs baseline: 1.7505x; 1.6743x over previous
//
#include <hip/hip_runtime.h>
#include <hip/hip_bf16.h>

// ---------------- helpers ----------------
using short8 = __attribute__((ext_vector_type(8))) short;
using f32x4  = __attribute__((ext_vector_type(4))) float;

__device__ __forceinline__ unsigned short f2bf(float f) {
  union { float f; unsigned int u; } x; x.f = f;
  unsigned int r = (x.u + 0x7fffu + ((x.u >> 16) & 1u)) >> 16;
  return (unsigned short)r;
}

__device__ __forceinline__ void gld_lds16(const short* gp, short* lp) {
  __builtin_amdgcn_global_load_lds((const __attribute__((address_space(1))) void*)gp,
                                   (__attribute__((address_space(3))) void*)lp, 16, 0, 0);
}

// ------- merged cast kernel -------------------------------------------------
// blocks [0,8192):      x -> xb (bf16, straight)
// blocks [8192,9216):   Wo -> U slot1 (straight)
// blocks [9216,9472):   Wq -> V slot0 (WqT, 64x64 LDS transpose)
// blocks [9472,9728):   Wk -> U slot0 (WkT)
// blocks [9728,9984):   Wv -> V slot1 (WvT)
// blocks [0,8):         also zero the 8192-float row-sum buffer (in ws).
__global__ __launch_bounds__(256) void cast_all(const float* __restrict__ x,
                                                const float* __restrict__ Wq,
                                                const float* __restrict__ Wk,
                                                const float* __restrict__ Wv,
                                                const float* __restrict__ Wo,
                                                short* __restrict__ xb,
                                                short* __restrict__ U,
                                                short* __restrict__ V,
                                                float4* __restrict__ sums4) {
  const int bid = blockIdx.x;
  const int tid = threadIdx.x;
  if (bid < 9216) {
    const float4* src;
    short* dst;
    const int i = bid * 256 + tid;
    if (bid < 8192) {
      src = (const float4*)x + i;
      dst = xb + 4ll * i;
    } else {
      const int off = i - 2097152;          // 0..262143 within Wo
      src = (const float4*)Wo + off;
      dst = U + 1048576 + 4ll * off;
    }
    float4 f = *src;
    short4 o;
    o.x = (short)f2bf(f.x); o.y = (short)f2bf(f.y);
    o.z = (short)f2bf(f.z); o.w = (short)f2bf(f.w);
    *(short4*)dst = o;
    if (bid < 8) sums4[bid * 256 + tid] = float4{0.f, 0.f, 0.f, 0.f};
  } else {
    // transpose: tile (by,bx) of W -> tile (bx,by) of dst
    __shared__ short tls[64][65];
    const int t  = bid - 9216;
    const int w  = t >> 8;                  // 0=Wq,1=Wk,2=Wv
    const int ti = t & 255;
    const int bx = ti & 15, by = ti >> 4;
    const float* src = (w == 0) ? Wq : (w == 1) ? Wk : Wv;
    short* dst = (w == 0) ? V : (w == 1) ? U : V + 1048576;
    const int r  = tid >> 4;                // 0..15
    const int c4 = (tid & 15) * 4;          // 0..60 step 4
#pragma unroll
    for (int s = 0; s < 4; ++s) {
      float4 f = *(const float4*)(src + (long long)(by * 64 + r + s * 16) * 1024 + bx * 64 + c4);
      tls[r + s * 16][c4 + 0] = (short)f2bf(f.x);
      tls[r + s * 16][c4 + 1] = (short)f2bf(f.y);
      tls[r + s * 16][c4 + 2] = (short)f2bf(f.z);
      tls[r + s * 16][c4 + 3] = (short)f2bf(f.w);
    }
    __syncthreads();
#pragma unroll
    for (int s = 0; s < 4; ++s) {
      const int a = r + s * 16;
      short4 o;
      o.x = tls[c4 + 0][a]; o.y = tls[c4 + 1][a];
      o.z = tls[c4 + 2][a]; o.w = tls[c4 + 3][a];
      *(short4*)(dst + (long long)(bx * 64 + a) * 1024 + by * 64 + c4) = o;
    }
  }
}

// ---------------- m97-style GEMM: C = A(MxK) * B(NxK)^T, XCD-swizzled ------
// 1-D grid, id = x*ng + g, g=(y,z): blocks sharing an A-row-tile are
// congruent mod 8 -> same XCD -> A-reuse from its L2.
// LDS tiles XOR-swizzled (chunk c of row r at slot c^(r&7)): 0 bank conflicts.
// Swapped mfma operands (except vo region): lane holds row=fr, cols rb..rb+3
// -> packed stores.
// MODE 1: bf16 row-major, z-batched (small weight-product GEMMs)
// MODE 2: merged t/vo projection. bx<8: t row-major; bx>=8: vo transposed
//         into vt=Cv+8388608: [b*4194304 + c*4096 + s], packed along s.
// MODE 4: QK^T + exp(scale*s) fused, bf16 packed stores, row-sum atomics.
// MODE 6: PV, 1/rowsum normalization, fp32 float4 stores (final output).
//
// NOTE (r1-r3 post-mortem): three attempts at a 256x256-tile counted-vmcnt
// pipelined kernel (gemm8) failed — r1/r2 the allocator pinned VGPR=128
// forcing ~690 MB/dispatch scratch spill (WRITE_SIZE 750 MB, MfmaUtil 5%);
// r3's 16-wave spill-free variant passed fresh-run correctness but diverged
// under graph replay (timing-dependent race in the hand-rolled vmcnt/barrier
// schedule; the spills in r1/r2 had been masking it). Custom sync structures
// need a multi-run race screen this harness can't provide. This file is the
// verified baseline structure (do not swap in unverified schedules).
template <int MODE>
__global__ __launch_bounds__(256) void gemm_bt(const short* __restrict__ A,
                                               const short* __restrict__ B,
                                               void* __restrict__ Cv,
                                               float* __restrict__ sums,
                                               int K, int ldc, float scale,
                                               long long aStr, long long bStr,
                                               long long cStr, int gy, int ng) {
  __shared__ short lA[128 * 64];
  __shared__ short lB[128 * 64];
  const int bid = blockIdx.x;
  const int bx  = bid / ng;
  const int g   = bid % ng;
  const int by  = g % gy;
  const long long z = g / gy;
  const int tid = threadIdx.x;
  const int w   = tid >> 6;     // wave 0..3
  const int l   = tid & 63;     // lane
  const int wm  = w >> 1, wn = w & 1;
  const long long tm = (long long)by * 128;
  const long long tn = (long long)bx * 128;
  A += z * aStr;
  B += z * bStr;

  const bool swp = (MODE == 2) ? (bx < 8) : true;

  f32x4 acc[4][4] = {};

  const int lr   = l >> 3;                         // row-in-segment
  const int scw  = ((l & 7) ^ (lr & 7)) * 8;       // swizzled fetch chunk (shorts)
  const int q4   = l >> 4;                         // quad
  const int fr   = l & 15;                         // m (or n) within 16-tile
  const int xr   = fr & 7;                         // row-phase for read swizzle

  for (int k0 = 0; k0 < K; k0 += 64) {
#pragma unroll
    for (int t = 0; t < 4; ++t) {
      const int seg = w * 4 + t;
      gld_lds16(A + (tm + seg * 8 + lr) * (long long)K + k0 + scw, &lA[seg * 512]);
      gld_lds16(B + (tn + seg * 8 + lr) * (long long)K + k0 + scw, &lB[seg * 512]);
    }
    __syncthreads();
#pragma unroll
    for (int kk = 0; kk < 64; kk += 32) {
      const int cs = ((((kk >> 3)) + q4) ^ xr) << 3;   // swizzled chunk offset
      short8 af[4], bfr[4];
#pragma unroll
      for (int i = 0; i < 4; ++i)
        af[i] = *(const short8*)&lA[(wm * 64 + i * 16 + fr) * 64 + cs];
#pragma unroll
      for (int j = 0; j < 4; ++j)
        bfr[j] = *(const short8*)&lB[(wn * 64 + j * 16 + fr) * 64 + cs];
      if (swp) {
#pragma unroll
        for (int i = 0; i < 4; ++i)
#pragma unroll
          for (int j = 0; j < 4; ++j)
            acc[i][j] = __builtin_amdgcn_mfma_f32_16x16x32_bf16(bfr[j], af[i], acc[i][j], 0, 0, 0);
      } else {
#pragma unroll
        for (int i = 0; i < 4; ++i)
#pragma unroll
          for (int j = 0; j < 4; ++j)
            acc[i][j] = __builtin_amdgcn_mfma_f32_16x16x32_bf16(af[i], bfr[j], acc[i][j], 0, 0, 0);
      }
    }
    __syncthreads();
  }

  const int rb = (l >> 4) * 4;   // col base within 16-tile (swapped layout)

  if (MODE == 1) {
    unsigned short* dst = (unsigned short*)Cv + z * cStr;
#pragma unroll
    for (int i = 0; i < 4; ++i) {
      const long long row = tm + wm * 64 + i * 16 + fr;
#pragma unroll
      for (int j = 0; j < 4; ++j) {
        const long long colb = tn + wn * 64 + j * 16 + rb;
        short4 pk;
        pk.x = (short)f2bf(acc[i][j][0]); pk.y = (short)f2bf(acc[i][j][1]);
        pk.z = (short)f2bf(acc[i][j][2]); pk.w = (short)f2bf(acc[i][j][3]);
        *(short4*)(dst + row * ldc + colb) = pk;
      }
    }
  } else if (MODE == 2) {
    if (swp) {   // t region: row-major, packed
      unsigned short* dst = (unsigned short*)Cv;
      const int cb0 = (int)tn + wn * 64;
#pragma unroll
      for (int i = 0; i < 4; ++i) {
        const long long row = tm + wm * 64 + i * 16 + fr;
#pragma unroll
        for (int j = 0; j < 4; ++j) {
          const int colb = cb0 + j * 16 + rb;
          short4 pk;
          pk.x = (short)f2bf(acc[i][j][0]); pk.y = (short)f2bf(acc[i][j][1]);
          pk.z = (short)f2bf(acc[i][j][2]); pk.w = (short)f2bf(acc[i][j][3]);
          *(short4*)(dst + row * 1024 + colb) = pk;
        }
      }
    } else {     // vo region: normal layout, pack along sequence dim
      unsigned short* dst = (unsigned short*)Cv + 8388608ll;
      const int cb0 = (int)(tn - 1024) + wn * 64;
#pragma unroll
      for (int i = 0; i < 4; ++i)
#pragma unroll
        for (int j = 0; j < 4; ++j) {
          const long long row0 = tm + wm * 64 + i * 16 + rb;
          const long long b = row0 >> 12, s0 = row0 & 4095;
          const int c = cb0 + j * 16 + fr;
          short4 pk;
          pk.x = (short)f2bf(acc[i][j][0]); pk.y = (short)f2bf(acc[i][j][1]);
          pk.z = (short)f2bf(acc[i][j][2]); pk.w = (short)f2bf(acc[i][j][3]);
          *(short4*)(dst + b * 4194304ll + (long long)c * 4096 + s0) = pk;
        }
    }
  } else if (MODE == 4) {
    unsigned short* dst = (unsigned short*)Cv + z * cStr;
    float* sm = sums + z * 4096;
#pragma unroll
    for (int i = 0; i < 4; ++i) {
      const long long row = tm + wm * 64 + i * 16 + fr;
      float rs = 0.f;
#pragma unroll
      for (int j = 0; j < 4; ++j) {
        const long long colb = tn + wn * 64 + j * 16 + rb;
        short4 pk;
        float e0 = __expf(acc[i][j][0] * scale);
        float e1 = __expf(acc[i][j][1] * scale);
        float e2 = __expf(acc[i][j][2] * scale);
        float e3 = __expf(acc[i][j][3] * scale);
        rs += (e0 + e1) + (e2 + e3);
        pk.x = (short)f2bf(e0); pk.y = (short)f2bf(e1);
        pk.z = (short)f2bf(e2); pk.w = (short)f2bf(e3);
        *(short4*)(dst + row * ldc + colb) = pk;
      }
      rs += __shfl_xor(rs, 16);
      rs += __shfl_xor(rs, 32);
      if (l < 16) atomicAdd(sm + tm + wm * 64 + i * 16 + l, rs);
    }
  } else {  // MODE 6: fp32 normalized output
    float* dst = (float*)Cv + z * cStr;
    const float* sm = sums + z * 4096;
#pragma unroll
    for (int i = 0; i < 4; ++i) {
      const long long row = tm + wm * 64 + i * 16 + fr;
      const float inv = 1.0f / sm[row];
#pragma unroll
      for (int j = 0; j < 4; ++j) {
        const long long colb = tn + wn * 64 + j * 16 + rb;
        f32x4 o;
        o[0] = acc[i][j][0] * inv; o[1] = acc[i][j][1] * inv;
        o[2] = acc[i][j][2] * inv; o[3] = acc[i][j][3] * inv;
        *(f32x4*)(dst + row * ldc + colb) = o;
      }
    }
  }
}

// ---------------- launch ----------------
extern "C" void kernel_launch(void* const* d_in, const int* in_sizes, int n_in,
                              void* d_out, int out_size, void* d_ws, size_t ws_size,
                              hipStream_t stream) {
  const float* x  = (const float*)d_in[0];
  const float* Wq = (const float*)d_in[1];
  const float* Wk = (const float*)d_in[2];
  const float* Wv = (const float*)d_in[3];
  const float* Wo = (const float*)d_in[4];
  float* out = (float*)d_out;

  // Algebra: scores = x·(Wq^T·Wk)·x^T, out = P_norm·x·(Wo·Wv)^T.
  // W2 slice0 = Wqk^T = Wk^T·Wq  (B operand for t = x·Wqk)
  // W2 slice1 = Wvo   = Wo·Wv    (B operand for vo = x·Wvo^T)
  // Small GEMM z-batch: U=[WkT; Wo], V=[WqT; WvT], C_z = U_z·V_z^T.
  //
  // ws layout (bytes):
  // [0,16M)    xb   8192x1024 bf16 (alive through QK: scores B operand)
  // [16M,20M)  U    [WkT; Wo]      [20M,24M) V [WqT; WvT]
  // [24M,28M)  W2   [WqkT; Wvo]
  // [28M,44M)  t    8192x1024 bf16  [44M,60M) vt[2][1024][4096] (vo^T)
  // [60M,+32K) sums 8192 fp32 (zeroed in cast_all)
  // [88M,152M) sc   2 x 4096x4096 bf16 scores (batched path)
  char* ws = (char*)d_ws;
  short* xb = (short*)ws;
  short* U  = (short*)(ws + (16ll << 20));
  short* V  = (short*)(ws + (20ll << 20));
  short* W2 = (short*)(ws + (24ll << 20));
  short* t  = (short*)(ws + (28ll << 20));
  short* vt = t + 8388608;
  float* sums = (float*)(ws + (60ll << 20));
  short* sc = (short*)(ws + (88ll << 20));

  const bool batched = ws_size >= 159383552ull;  // need 152 MiB
  dim3 blk(256);

  // casts + 3 weight transposes + zero sums: 8192+1024+768 = 9984 blocks
  cast_all<<<9984, blk, 0, stream>>>(x, Wq, Wk, Wv, Wo, xb, U, V, (float4*)sums);

  // W2 = [WkT·WqT^T ; Wo·WvT^T], z=2: M=N=K=1024, grid x=8, g=(y8,z2)=16
  gemm_bt<1><<<8 * 16, blk, 0, stream>>>(U, V, W2, nullptr, 1024, 1024, 1.f,
                                         1048576ll, 1048576ll, 1048576ll, 8, 16);

  // merged t/vo projection: M=8192, N=2048, K=1024; grid x=16, g=64
  gemm_bt<2><<<16 * 64, blk, 0, stream>>>(xb, W2, t, nullptr, 1024, 1024, 1.f,
                                          0, 0, 0, 64, 64);

  if (batched) {
    // scores = t·xb^T + exp, both batches: x=32, g=(y32,z2)=64
    gemm_bt<4><<<32 * 64, blk, 0, stream>>>(t, xb, sc, sums, 1024, 4096, 0.03125f,
                                            4194304ll, 4194304ll, 16777216ll, 32, 64);
    // P·vo + normalize -> d_out fp32, both batches: x=8, g=64
    gemm_bt<6><<<8 * 64, blk, 0, stream>>>(sc, vt, out, sums, 4096, 1024, 1.f,
                                           16777216ll, 4194304ll, 4194304ll, 32, 64);
  } else {
    for (int b = 0; b < 2; ++b) {
      short* tb  = t  + (long long)b * 4194304;
      short* xbb = xb + (long long)b * 4194304;
      short* vb  = vt + (long long)b * 4194304;
      float* ob  = out + (long long)b * 4194304;
      float* smb = sums + (long long)b * 4096;
      gemm_bt<4><<<32 * 32, blk, 0, stream>>>(tb, xbb, sc, smb, 1024, 4096, 0.03125f,
                                              0, 0, 0, 32, 32);
      gemm_bt<6><<<8 * 32, blk, 0, stream>>>(sc, vb, ob, smb, 4096, 1024, 1.f,
                                             0, 0, 0, 32, 32);
    }
  }
}